// Round 9
// baseline (610.572 us; speedup 1.0000x reference)
//
#include <hip/hip_runtime.h>
#include <stdint.h>

typedef unsigned int u32;
typedef unsigned short u16;

#define NSTEP 16
#define DTS (1.0f/16.0f)

// ws layout (float index): [0] dtype flag; [8..71] M = W2 - W2^T (fp32);
// [72..103] W2 columns packed half2 (u32 bits): w2c[j*4+kk] = pk(W2[2kk][j], W2[2kk+1][j]);
// [112 + s*32 + e] antisym(W0 + t(s)*W1) upper-tri (fp32), e<28, s = step*4+stage
#define TAB_FLAG 0
#define TAB_W2M  8
#define TAB_W2C  72
#define TAB_WT   112

typedef _Float16 f16;
typedef f16 h2 __attribute__((ext_vector_type(2)));

__device__ __forceinline__ float b2f(u16 h){ return __uint_as_float(((u32)h) << 16); }
__device__ __forceinline__ float bflo(u32 w){ return __uint_as_float(w << 16); }
__device__ __forceinline__ float bfhi(u32 w){ return __uint_as_float(w & 0xffff0000u); }
__device__ __forceinline__ u32 f2b(float f){
  u32 u = __float_as_uint(f);
  return (u + 0x7fffu + ((u >> 16) & 1u)) >> 16;   // RNE to bf16
}
__host__ __device__ constexpr int TRI(int i, int j){ return i*7 - (i*(i-1))/2 + (j-i-1); }

__device__ __forceinline__ u32 pkh(float a, float b){
  return __builtin_bit_cast(u32, __builtin_amdgcn_cvt_pkrtz(a, b));
}
__device__ __forceinline__ h2 u2h(u32 x){ return __builtin_bit_cast(h2, x); }

// 8-length dot of half2-packed rows (4 u32 each), fp32 accumulate via v_dot2_f32_f16
// (fp16 products are exact in fp32; fp32 accumulation -> baseline-identical numerics)
__device__ __forceinline__ float dot8h(const u32* a, const u32* b){
  float s = __builtin_amdgcn_fdot2(u2h(a[0]), u2h(b[0]), 0.0f, false);
  s = __builtin_amdgcn_fdot2(u2h(a[1]), u2h(b[1]), s, false);
  s = __builtin_amdgcn_fdot2(u2h(a[2]), u2h(b[2]), s, false);
  s = __builtin_amdgcn_fdot2(u2h(a[3]), u2h(b[3]), s, false);
  return s;
}
// F element with antisymmetry (compile-time i,k only)
__device__ __forceinline__ float Fel(const float* Fu, int i, int k){
  if (i == k) return 0.0f;
  return (i < k) ? Fu[TRI(i,k)] : -Fu[TRI(k,i)];
}

__global__ void prep_kernel(const void* __restrict__ W0v, const void* __restrict__ W1v,
                            const void* __restrict__ W2v, float* __restrict__ ws)
{
  __shared__ int sflag;
  __shared__ float sW0[64], sW1[64], sW2[64];
  int t = threadIdx.x;

  if (t == 0) {
    const u16* w2h = (const u16*)W2v;
    int ok = 1;
    for (int x = 0; x < 64; ++x) {
      float v = b2f(w2h[x]);
      if (!(v > -1024.0f && v < 1024.0f)) { ok = 0; break; }
    }
    sflag = ok;
    ws[TAB_FLAG] = (float)ok;
  }
  __syncthreads();
  int isbf = sflag;

  if (t < 64) {
    if (isbf) {
      sW0[t] = b2f(((const u16*)W0v)[t]);
      sW1[t] = b2f(((const u16*)W1v)[t]);
      sW2[t] = b2f(((const u16*)W2v)[t]);
    } else {
      sW0[t] = ((const float*)W0v)[t];
      sW1[t] = ((const float*)W1v)[t];
      sW2[t] = ((const float*)W2v)[t];
    }
  }
  __syncthreads();

  if (t < 64) {
    int i = t >> 3, j = t & 7;
    ws[TAB_W2M + t] = sW2[t] - sW2[j*8+i];
  }
  if (t < 32) {
    int j = t >> 2, kk = t & 3;
    ((u32*)ws)[TAB_W2C + t] = pkh(sW2[(2*kk)*8 + j], sW2[(2*kk+1)*8 + j]);
  }
  for (int idx = t; idx < 64*28; idx += 256) {
    int s = idx / 28;
    int e = idx - s*28;
    int i = 0, r = e;
    while (r >= 7 - i) { r -= 7 - i; ++i; }
    int j = i + 1 + r;
    int step = s >> 2, st = s & 3;
    float toff = (st == 0) ? 0.0f : ((st == 3) ? 1.0f : 0.5f);
    float tt = ((float)step + toff) * DTS;
    float w0a = 0.5f*(sW0[i*8+j] - sW0[j*8+i]);
    float w1a = 0.5f*(sW1[i*8+j] - sW1[j*8+i]);
    ws[TAB_WT + s*32 + e] = fmaf(tt, w1a, w0a);
  }
}

// NO register attributes: R8 proved true pressure ~156 regs with zero spill at
// a >=256 budget, but amdgpu_num_vgpr(256) wrote 256 into the kernel descriptor
// and the HW allocates wave slots from the DESCRIPTOR -> 1 wave/SIMD pin
// (occupancy 11.9% across R0/R5/R7/R8; descriptor~128 configs got 2 waves/SIMD).
// With an honest descriptor (~160), expect 2-3 waves/SIMD.
__global__ void __attribute__((amdgpu_flat_work_group_size(64,64)))
flow_kernel(const void* __restrict__ U0v, const void* __restrict__ EPSv,
            const float* __restrict__ ws, void* __restrict__ outv, int B)
{
  // per-thread-private V/E storage, wave-transposed: [e:32][lane:64] uint2.
  // Lane-contiguous 8B accesses -> free 2-way bank aliasing; no cross-thread
  // sharing -> no barriers. 16 KiB/block -> LDS allows 10 blocks/CU.
  __shared__ uint2 ve[64*32];
  const int tid = threadIdx.x;   // 0..63
  const int b = blockIdx.x * 64 + tid;
  uint2* myve = &ve[tid];        // element e at myve[e*64]
  if (b >= B) return;
  const int isbf = (ws[TAB_FLAG] != 0.0f);

  float Us[64];   // canonical carried state: fp32 (precision-critical)

  // ---- setup: decode U -> Us; V fp32; E = V*M; pack V,E -> LDS ----
  {
    float V[64];
    if (isbf) {
      const uint4* pu = (const uint4*)((const u16*)U0v + (size_t)b*64);
      const uint4* pv = (const uint4*)((const u16*)EPSv + (size_t)b*64);
      #pragma unroll
      for (int q = 0; q < 8; ++q) {
        uint4 xu = pu[q];
        uint4 xv = pv[q];
        Us[8*q+0]=bflo(xu.x); Us[8*q+1]=bfhi(xu.x);
        Us[8*q+2]=bflo(xu.y); Us[8*q+3]=bfhi(xu.y);
        Us[8*q+4]=bflo(xu.z); Us[8*q+5]=bfhi(xu.z);
        Us[8*q+6]=bflo(xu.w); Us[8*q+7]=bfhi(xu.w);
        V[8*q+0]=bflo(xv.x); V[8*q+1]=bfhi(xv.x);
        V[8*q+2]=bflo(xv.y); V[8*q+3]=bfhi(xv.y);
        V[8*q+4]=bflo(xv.z); V[8*q+5]=bfhi(xv.z);
        V[8*q+6]=bflo(xv.w); V[8*q+7]=bfhi(xv.w);
      }
    } else {
      const float4* pu = (const float4*)((const float*)U0v + (size_t)b*64);
      const float4* pv = (const float4*)((const float*)EPSv + (size_t)b*64);
      #pragma unroll
      for (int q = 0; q < 16; ++q) {
        float4 xu = pu[q];
        float4 xv = pv[q];
        Us[4*q+0]=xu.x; Us[4*q+1]=xu.y; Us[4*q+2]=xu.z; Us[4*q+3]=xu.w;
        V[4*q+0]=xv.x; V[4*q+1]=xv.y; V[4*q+2]=xv.z; V[4*q+3]=xv.w;
      }
    }
    const float* M = ws + TAB_W2M;
    #pragma unroll
    for (int i = 0; i < 8; ++i) {
      float e[8];
      #pragma unroll
      for (int j = 0; j < 8; ++j) {
        float s = V[i*8+0] * M[0*8+j];
        #pragma unroll
        for (int k = 1; k < 8; ++k) s = fmaf(V[i*8+k], M[k*8+j], s);
        e[j] = s;
      }
      myve[(2*i+0)*64]  = make_uint2(pkh(V[i*8+0],V[i*8+1]), pkh(V[i*8+2],V[i*8+3]));
      myve[(2*i+1)*64]  = make_uint2(pkh(V[i*8+4],V[i*8+5]), pkh(V[i*8+6],V[i*8+7]));
      myve[(16+2*i)*64] = make_uint2(pkh(e[0],e[1]), pkh(e[2],e[3]));
      myve[(17+2*i)*64] = make_uint2(pkh(e[4],e[5]), pkh(e[6],e[7]));
    }
  }

  // uniform packed W2 columns (compiler keeps these scalar)
  u32 w2c[32];
  #pragma unroll
  for (int x = 0; x < 32; ++x) w2c[x] = ((const u32*)ws)[TAB_W2C + x];

  float lj = 0.0f;

  #pragma unroll 1
  for (int step = 0; step < NSTEP; ++step) {
    float acc[64];                 // RK4 k-accumulator, fp32 (baseline numerics)
    u32 Uh[32];                    // current-stage U rows, fp16-packed
    #pragma unroll
    for (int x = 0; x < 32; ++x) {
      Uh[x] = pkh(Us[2*x], Us[2*x+1]);
      acc[2*x] = 0.0f; acc[2*x+1] = 0.0f;
    }

    #pragma unroll 1
    for (int stage = 0; stage < 4; ++stage) {
      const float* wt = ws + TAB_WT + (size_t)(((step << 2) | stage) << 5);

      // ---- logj pass 1: D_ij = dot(V_i,U_j) - dot(V_j,U_i) for i<j ----
      // 1-row-ahead prefetch: row r+1's ds_reads issue before row r's dots.
      float D[28];
      {
        uint2 va = myve[0*64], vb = myve[1*64];
        #pragma unroll
        for (int r = 0; r < 8; ++r) {
          uint2 van, vbn;
          if (r < 7) { van = myve[(2*r+2)*64]; vbn = myve[(2*r+3)*64]; }
          u32 vr[4] = {va.x, va.y, vb.x, vb.y};
          #pragma unroll
          for (int m = 0; m < 8; ++m) {
            if (m == r) continue;
            float dv = dot8h(vr, Uh + m*4);
            if (m > r) D[TRI(r,m)] = dv;
            else       D[TRI(m,r)] -= dv;
          }
          va = van; vb = vbn;
        }
      }
      // ---- logj pass 2: Ssum = sum_{r!=m} de_rm * (m>r ? D_rm : -D_mr) ----
      float Ssum = 0.0f;
      {
        uint2 ea = myve[16*64], eb = myve[17*64];
        #pragma unroll
        for (int r = 0; r < 8; ++r) {
          uint2 ean, ebn;
          if (r < 7) { ean = myve[(16+2*r+2)*64]; ebn = myve[(16+2*r+3)*64]; }
          u32 er[4] = {ea.x, ea.y, eb.x, eb.y};
          #pragma unroll
          for (int m = 0; m < 8; ++m) {
            if (m == r) continue;
            float de = dot8h(er, Uh + m*4);
            Ssum = fmaf(de, (m > r) ? D[TRI(r,m)] : -D[TRI(m,r)], Ssum);
          }
          ea = ean; eb = ebn;
        }
      }
      float cl = (stage == 1 || stage == 2) ? (DTS/6.0f) : (DTS/12.0f); // dt/6 * w * 0.5
      lj = fmaf(cl, Ssum, lj);

      // ---- F upper tri, row-streamed: F_ij = wt_ij + 0.5*(S_ij - S_ji), S = (U W2) U^T ----
      float Fu[28];
      #pragma unroll
      for (int r = 0; r < 8; ++r) {
        float ar[8];
        #pragma unroll
        for (int j = 0; j < 8; ++j) ar[j] = dot8h(Uh + r*4, w2c + j*4);  // A_rj
        u32 Ah[4];
        #pragma unroll
        for (int kk = 0; kk < 4; ++kk) Ah[kk] = pkh(ar[2*kk], ar[2*kk+1]);
        #pragma unroll
        for (int j = 0; j < 8; ++j) {
          if (j == r) continue;
          float da = dot8h(Ah, Uh + j*4);          // S_rj = dot(A_r, U_j)
          if (j > r) Fu[TRI(r,j)] = fmaf(0.5f, da, wt[TRI(r,j)]);
          else       Fu[TRI(j,r)] = fmaf(-0.5f, da, Fu[TRI(j,r)]);
        }
      }

      // ---- F rows packed fp16; Fu dies here ----
      u32 Fh[32];
      #pragma unroll
      for (int i = 0; i < 8; ++i)
        #pragma unroll
        for (int kk = 0; kk < 4; ++kk)
          Fh[i*4+kk] = pkh(Fel(Fu, i, 2*kk), Fel(Fu, i, 2*kk+1));

      // ---- U columns fp16-packed, rebuilt from Uh by 16-bit extraction ----
      u32 Uc[32];
      #pragma unroll
      for (int kk = 0; kk < 4; ++kk) {
        #pragma unroll
        for (int jh = 0; jh < 4; ++jh) {
          u32 A  = Uh[(2*kk)*4 + jh];      // cols 2jh,2jh+1 of row 2kk
          u32 Bv = Uh[(2*kk+1)*4 + jh];    // cols 2jh,2jh+1 of row 2kk+1
          Uc[(2*jh+0)*4 + kk] = (A & 0xffffu) | (Bv << 16);
          Uc[(2*jh+1)*4 + kk] = (A >> 16) | (Bv & 0xffff0000u);
        }
      }

      // ---- K = F*U: fp32 dot accumulate; pairwise kv -> immediate Uh pack ----
      float wa = (stage == 1 || stage == 2) ? 2.0f : 1.0f;
      float cs = (stage == 2) ? DTS : (0.5f*DTS);
      #pragma unroll
      for (int i = 0; i < 8; ++i) {
        #pragma unroll
        for (int jh = 0; jh < 4; ++jh) {
          float kva = dot8h(Fh + i*4, Uc + (2*jh+0)*4);
          float kvb = dot8h(Fh + i*4, Uc + (2*jh+1)*4);
          acc[i*8+2*jh+0] = fmaf(wa, kva, acc[i*8+2*jh+0]);
          acc[i*8+2*jh+1] = fmaf(wa, kvb, acc[i*8+2*jh+1]);
          if (stage < 3)
            Uh[i*4+jh] = pkh(fmaf(cs, kva, Us[i*8+2*jh+0]),
                             fmaf(cs, kvb, Us[i*8+2*jh+1]));
        }
      }
    }
    // ---- fp32 carried-state update: Us += dt/6 * acc ----
    #pragma unroll
    for (int x = 0; x < 64; ++x) Us[x] = fmaf(DTS/6.0f, acc[x], Us[x]);
  }

  // ---- store ----
  if (isbf) {
    u16* outU = (u16*)outv;
    uint4* po = (uint4*)(outU + (size_t)b*64);
    #pragma unroll
    for (int q = 0; q < 8; ++q) {
      uint4 o;
      o.x = f2b(Us[8*q+0]) | (f2b(Us[8*q+1]) << 16);
      o.y = f2b(Us[8*q+2]) | (f2b(Us[8*q+3]) << 16);
      o.z = f2b(Us[8*q+4]) | (f2b(Us[8*q+5]) << 16);
      o.w = f2b(Us[8*q+6]) | (f2b(Us[8*q+7]) << 16);
      po[q] = o;
    }
    outU[(size_t)B*64 + b] = (u16)f2b(lj);
  } else {
    float* outU = (float*)outv;
    float4* po = (float4*)(outU + (size_t)b*64);
    #pragma unroll
    for (int q = 0; q < 16; ++q) {
      po[q] = make_float4(Us[4*q+0], Us[4*q+1], Us[4*q+2], Us[4*q+3]);
    }
    outU[(size_t)B*64 + b] = lj;
  }
}

extern "C" void kernel_launch(void* const* d_in, const int* in_sizes, int n_in,
                              void* d_out, int out_size, void* d_ws, size_t ws_size,
                              hipStream_t stream) {
  const void* U0  = d_in[0];
  const void* EPS = d_in[1];
  const void* W0  = d_in[2];
  const void* W1  = d_in[3];
  const void* W2  = d_in[4];
  float* ws = (float*)d_ws;
  int B = in_sizes[0] / 64;

  hipLaunchKernelGGL(prep_kernel, dim3(1), dim3(256), 0, stream, W0, W1, W2, ws);
  hipLaunchKernelGGL(flow_kernel, dim3((B + 63) / 64), dim3(64), 0, stream,
                     U0, EPS, ws, d_out, B);
}

// Round 11
// 595.179 us; speedup vs baseline: 1.0259x; 1.0259x over previous
//
#include <hip/hip_runtime.h>
#include <stdint.h>

typedef unsigned int u32;
typedef unsigned short u16;

#define NSTEP 16
#define DTS (1.0f/16.0f)

// ws layout (float index): [0] dtype flag; [8..71] M = W2 - W2^T (fp32);
// [72..103] W2 columns packed half2 (u32 bits): w2c[j*4+kk] = pk(W2[2kk][j], W2[2kk+1][j]);
// [112 + s*32 + e] antisym(W0 + t(s)*W1) upper-tri (fp32), e<28, s = step*4+stage
#define TAB_FLAG 0
#define TAB_W2M  8
#define TAB_W2C  72
#define TAB_WT   112

typedef _Float16 f16;
typedef f16 h2 __attribute__((ext_vector_type(2)));

__device__ __forceinline__ float b2f(u16 h){ return __uint_as_float(((u32)h) << 16); }
__device__ __forceinline__ float bflo(u32 w){ return __uint_as_float(w << 16); }
__device__ __forceinline__ float bfhi(u32 w){ return __uint_as_float(w & 0xffff0000u); }
__device__ __forceinline__ u32 f2b(float f){
  u32 u = __float_as_uint(f);
  return (u + 0x7fffu + ((u >> 16) & 1u)) >> 16;   // RNE to bf16
}
__host__ __device__ constexpr int TRI(int i, int j){ return i*7 - (i*(i-1))/2 + (j-i-1); }

__device__ __forceinline__ u32 pkh(float a, float b){
  return __builtin_bit_cast(u32, __builtin_amdgcn_cvt_pkrtz(a, b));
}
__device__ __forceinline__ h2 u2h(u32 x){ return __builtin_bit_cast(h2, x); }

// 8-length dot of half2-packed rows (4 u32 each), fp32 accumulate via v_dot2_f32_f16
// (fp16 products are exact in fp32; fp32 accumulation -> baseline-identical numerics)
__device__ __forceinline__ float dot8h(const u32* a, const u32* b){
  float s = __builtin_amdgcn_fdot2(u2h(a[0]), u2h(b[0]), 0.0f, false);
  s = __builtin_amdgcn_fdot2(u2h(a[1]), u2h(b[1]), s, false);
  s = __builtin_amdgcn_fdot2(u2h(a[2]), u2h(b[2]), s, false);
  s = __builtin_amdgcn_fdot2(u2h(a[3]), u2h(b[3]), s, false);
  return s;
}
// F element with antisymmetry (compile-time i,k only)
__device__ __forceinline__ float Fel(const float* Fu, int i, int k){
  if (i == k) return 0.0f;
  return (i < k) ? Fu[TRI(i,k)] : -Fu[TRI(k,i)];
}

__global__ void prep_kernel(const void* __restrict__ W0v, const void* __restrict__ W1v,
                            const void* __restrict__ W2v, float* __restrict__ ws)
{
  __shared__ int sflag;
  __shared__ float sW0[64], sW1[64], sW2[64];
  int t = threadIdx.x;

  if (t == 0) {
    const u16* w2h = (const u16*)W2v;
    int ok = 1;
    for (int x = 0; x < 64; ++x) {
      float v = b2f(w2h[x]);
      if (!(v > -1024.0f && v < 1024.0f)) { ok = 0; break; }
    }
    sflag = ok;
    ws[TAB_FLAG] = (float)ok;
  }
  __syncthreads();
  int isbf = sflag;

  if (t < 64) {
    if (isbf) {
      sW0[t] = b2f(((const u16*)W0v)[t]);
      sW1[t] = b2f(((const u16*)W1v)[t]);
      sW2[t] = b2f(((const u16*)W2v)[t]);
    } else {
      sW0[t] = ((const float*)W0v)[t];
      sW1[t] = ((const float*)W1v)[t];
      sW2[t] = ((const float*)W2v)[t];
    }
  }
  __syncthreads();

  if (t < 64) {
    int i = t >> 3, j = t & 7;
    ws[TAB_W2M + t] = sW2[t] - sW2[j*8+i];
  }
  if (t < 32) {
    int j = t >> 2, kk = t & 3;
    ((u32*)ws)[TAB_W2C + t] = pkh(sW2[(2*kk)*8 + j], sW2[(2*kk+1)*8 + j]);
  }
  for (int idx = t; idx < 64*28; idx += 256) {
    int s = idx / 28;
    int e = idx - s*28;
    int i = 0, r = e;
    while (r >= 7 - i) { r -= 7 - i; ++i; }
    int j = i + 1 + r;
    int step = s >> 2, st = s & 3;
    float toff = (st == 0) ? 0.0f : ((st == 3) ? 1.0f : 0.5f);
    float tt = ((float)step + toff) * DTS;
    float w0a = 0.5f*(sW0[i*8+j] - sW0[j*8+i]);
    float w1a = 0.5f*(sW1[i*8+j] - sW1[j*8+i]);
    ws[TAB_WT + s*32 + e] = fmaf(tt, w1a, w0a);
  }
}

// No register attributes (R9 config: VGPR 156, zero spill).
// NEW vs R9: the per-stage wt table (28 scalar SMEM loads/stage) is staged into
// block-shared LDS once at kernel start. SMEM shares lgkmcnt with ds_read but
// returns OUT-OF-ORDER -> any wait on an s_load result is a full lgkmcnt(0)
// drain; 28 s_loads interleaved with 32 ds_reads per stage forced repeated
// full drains (~the 67% stall at 33% issue efficiency). Pure-DS lgkm restores
// counted waits and makes the V/E prefetch effective.
__global__ void __attribute__((amdgpu_flat_work_group_size(64,64)))
flow_kernel(const void* __restrict__ U0v, const void* __restrict__ EPSv,
            const float* __restrict__ ws, void* __restrict__ outv, int B)
{
  // per-thread-private V/E storage, wave-transposed: [e:32][lane:64] uint2.
  // Lane-contiguous 8B accesses -> free 2-way bank aliasing; no cross-thread
  // sharing -> no barriers for ve. wts is block-shared (one barrier at start).
  // 16 KiB (ve) + 8 KiB (wts) = 24 KiB/block.
  __shared__ uint2 ve[64*32];
  __shared__ float wts[64*32];   // all 64 stages x 32 (28 used) wt entries
  const int tid = threadIdx.x;   // 0..63
  const int b = blockIdx.x * 64 + tid;
  uint2* myve = &ve[tid];        // element e at myve[e*64]

  // ---- stage wt table into LDS (block-shared, coalesced float4) ----
  {
    const float4* src = (const float4*)(ws + TAB_WT);   // 512 float4s
    float4* dst = (float4*)wts;
    #pragma unroll
    for (int k = 0; k < 8; ++k) dst[tid + k*64] = src[tid + k*64];
  }
  __syncthreads();
  if (b >= B) return;

  const int isbf = (ws[TAB_FLAG] != 0.0f);

  float Us[64];   // canonical carried state: fp32 (precision-critical)

  // ---- setup: decode U -> Us; V fp32; E = V*M; pack V,E -> LDS ----
  {
    float V[64];
    if (isbf) {
      const uint4* pu = (const uint4*)((const u16*)U0v + (size_t)b*64);
      const uint4* pv = (const uint4*)((const u16*)EPSv + (size_t)b*64);
      #pragma unroll
      for (int q = 0; q < 8; ++q) {
        uint4 xu = pu[q];
        uint4 xv = pv[q];
        Us[8*q+0]=bflo(xu.x); Us[8*q+1]=bfhi(xu.x);
        Us[8*q+2]=bflo(xu.y); Us[8*q+3]=bfhi(xu.y);
        Us[8*q+4]=bflo(xu.z); Us[8*q+5]=bfhi(xu.z);
        Us[8*q+6]=bflo(xu.w); Us[8*q+7]=bfhi(xu.w);
        V[8*q+0]=bflo(xv.x); V[8*q+1]=bfhi(xv.x);
        V[8*q+2]=bflo(xv.y); V[8*q+3]=bfhi(xv.y);
        V[8*q+4]=bflo(xv.z); V[8*q+5]=bfhi(xv.z);
        V[8*q+6]=bflo(xv.w); V[8*q+7]=bfhi(xv.w);
      }
    } else {
      const float4* pu = (const float4*)((const float*)U0v + (size_t)b*64);
      const float4* pv = (const float4*)((const float*)EPSv + (size_t)b*64);
      #pragma unroll
      for (int q = 0; q < 16; ++q) {
        float4 xu = pu[q];
        float4 xv = pv[q];
        Us[4*q+0]=xu.x; Us[4*q+1]=xu.y; Us[4*q+2]=xu.z; Us[4*q+3]=xu.w;
        V[4*q+0]=xv.x; V[4*q+1]=xv.y; V[4*q+2]=xv.z; V[4*q+3]=xv.w;
      }
    }
    const float* M = ws + TAB_W2M;
    #pragma unroll
    for (int i = 0; i < 8; ++i) {
      float e[8];
      #pragma unroll
      for (int j = 0; j < 8; ++j) {
        float s = V[i*8+0] * M[0*8+j];
        #pragma unroll
        for (int k = 1; k < 8; ++k) s = fmaf(V[i*8+k], M[k*8+j], s);
        e[j] = s;
      }
      myve[(2*i+0)*64]  = make_uint2(pkh(V[i*8+0],V[i*8+1]), pkh(V[i*8+2],V[i*8+3]));
      myve[(2*i+1)*64]  = make_uint2(pkh(V[i*8+4],V[i*8+5]), pkh(V[i*8+6],V[i*8+7]));
      myve[(16+2*i)*64] = make_uint2(pkh(e[0],e[1]), pkh(e[2],e[3]));
      myve[(17+2*i)*64] = make_uint2(pkh(e[4],e[5]), pkh(e[6],e[7]));
    }
  }

  // uniform packed W2 columns (compiler keeps these scalar)
  u32 w2c[32];
  #pragma unroll
  for (int x = 0; x < 32; ++x) w2c[x] = ((const u32*)ws)[TAB_W2C + x];

  float lj = 0.0f;

  #pragma unroll 1
  for (int step = 0; step < NSTEP; ++step) {
    float acc[64];                 // RK4 k-accumulator, fp32 (baseline numerics)
    u32 Uh[32];                    // current-stage U rows, fp16-packed
    #pragma unroll
    for (int x = 0; x < 32; ++x) {
      Uh[x] = pkh(Us[2*x], Us[2*x+1]);
      acc[2*x] = 0.0f; acc[2*x+1] = 0.0f;
    }

    #pragma unroll 1
    for (int stage = 0; stage < 4; ++stage) {
      const float* wt = wts + (((step << 2) | stage) << 5);   // LDS, in-order DS reads

      // ---- logj pass 1: D_ij = dot(V_i,U_j) - dot(V_j,U_i) for i<j ----
      // 1-row-ahead prefetch: row r+1's ds_reads issue before row r's dots.
      float D[28];
      {
        uint2 va = myve[0*64], vb = myve[1*64];
        #pragma unroll
        for (int r = 0; r < 8; ++r) {
          uint2 van, vbn;
          if (r < 7) { van = myve[(2*r+2)*64]; vbn = myve[(2*r+3)*64]; }
          u32 vr[4] = {va.x, va.y, vb.x, vb.y};
          #pragma unroll
          for (int m = 0; m < 8; ++m) {
            if (m == r) continue;
            float dv = dot8h(vr, Uh + m*4);
            if (m > r) D[TRI(r,m)] = dv;
            else       D[TRI(m,r)] -= dv;
          }
          va = van; vb = vbn;
        }
      }
      // ---- logj pass 2: Ssum = sum_{r!=m} de_rm * (m>r ? D_rm : -D_mr) ----
      float Ssum = 0.0f;
      {
        uint2 ea = myve[16*64], eb = myve[17*64];
        #pragma unroll
        for (int r = 0; r < 8; ++r) {
          uint2 ean, ebn;
          if (r < 7) { ean = myve[(16+2*r+2)*64]; ebn = myve[(16+2*r+3)*64]; }
          u32 er[4] = {ea.x, ea.y, eb.x, eb.y};
          #pragma unroll
          for (int m = 0; m < 8; ++m) {
            if (m == r) continue;
            float de = dot8h(er, Uh + m*4);
            Ssum = fmaf(de, (m > r) ? D[TRI(r,m)] : -D[TRI(m,r)], Ssum);
          }
          ea = ean; eb = ebn;
        }
      }
      float cl = (stage == 1 || stage == 2) ? (DTS/6.0f) : (DTS/12.0f); // dt/6 * w * 0.5
      lj = fmaf(cl, Ssum, lj);

      // ---- F upper tri, row-streamed: F_ij = wt_ij + 0.5*(S_ij - S_ji), S = (U W2) U^T ----
      float Fu[28];
      #pragma unroll
      for (int r = 0; r < 8; ++r) {
        float ar[8];
        #pragma unroll
        for (int j = 0; j < 8; ++j) ar[j] = dot8h(Uh + r*4, w2c + j*4);  // A_rj
        u32 Ah[4];
        #pragma unroll
        for (int kk = 0; kk < 4; ++kk) Ah[kk] = pkh(ar[2*kk], ar[2*kk+1]);
        #pragma unroll
        for (int j = 0; j < 8; ++j) {
          if (j == r) continue;
          float da = dot8h(Ah, Uh + j*4);          // S_rj = dot(A_r, U_j)
          if (j > r) Fu[TRI(r,j)] = fmaf(0.5f, da, wt[TRI(r,j)]);
          else       Fu[TRI(j,r)] = fmaf(-0.5f, da, Fu[TRI(j,r)]);
        }
      }

      // ---- F rows packed fp16; Fu dies here ----
      u32 Fh[32];
      #pragma unroll
      for (int i = 0; i < 8; ++i)
        #pragma unroll
        for (int kk = 0; kk < 4; ++kk)
          Fh[i*4+kk] = pkh(Fel(Fu, i, 2*kk), Fel(Fu, i, 2*kk+1));

      // ---- U columns fp16-packed, rebuilt from Uh by 16-bit extraction ----
      u32 Uc[32];
      #pragma unroll
      for (int kk = 0; kk < 4; ++kk) {
        #pragma unroll
        for (int jh = 0; jh < 4; ++jh) {
          u32 A  = Uh[(2*kk)*4 + jh];      // cols 2jh,2jh+1 of row 2kk
          u32 Bv = Uh[(2*kk+1)*4 + jh];    // cols 2jh,2jh+1 of row 2kk+1
          Uc[(2*jh+0)*4 + kk] = (A & 0xffffu) | (Bv << 16);
          Uc[(2*jh+1)*4 + kk] = (A >> 16) | (Bv & 0xffff0000u);
        }
      }

      // ---- K = F*U: fp32 dot accumulate; pairwise kv -> immediate Uh pack ----
      float wa = (stage == 1 || stage == 2) ? 2.0f : 1.0f;
      float cs = (stage == 2) ? DTS : (0.5f*DTS);
      #pragma unroll
      for (int i = 0; i < 8; ++i) {
        #pragma unroll
        for (int jh = 0; jh < 4; ++jh) {
          float kva = dot8h(Fh + i*4, Uc + (2*jh+0)*4);
          float kvb = dot8h(Fh + i*4, Uc + (2*jh+1)*4);
          acc[i*8+2*jh+0] = fmaf(wa, kva, acc[i*8+2*jh+0]);
          acc[i*8+2*jh+1] = fmaf(wa, kvb, acc[i*8+2*jh+1]);
          if (stage < 3)
            Uh[i*4+jh] = pkh(fmaf(cs, kva, Us[i*8+2*jh+0]),
                             fmaf(cs, kvb, Us[i*8+2*jh+1]));
        }
      }
    }
    // ---- fp32 carried-state update: Us += dt/6 * acc ----
    #pragma unroll
    for (int x = 0; x < 64; ++x) Us[x] = fmaf(DTS/6.0f, acc[x], Us[x]);
  }

  // ---- store ----
  if (isbf) {
    u16* outU = (u16*)outv;
    uint4* po = (uint4*)(outU + (size_t)b*64);
    #pragma unroll
    for (int q = 0; q < 8; ++q) {
      uint4 o;
      o.x = f2b(Us[8*q+0]) | (f2b(Us[8*q+1]) << 16);
      o.y = f2b(Us[8*q+2]) | (f2b(Us[8*q+3]) << 16);
      o.z = f2b(Us[8*q+4]) | (f2b(Us[8*q+5]) << 16);
      o.w = f2b(Us[8*q+6]) | (f2b(Us[8*q+7]) << 16);
      po[q] = o;
    }
    outU[(size_t)B*64 + b] = (u16)f2b(lj);
  } else {
    float* outU = (float*)outv;
    float4* po = (float4*)(outU + (size_t)b*64);
    #pragma unroll
    for (int q = 0; q < 16; ++q) {
      po[q] = make_float4(Us[4*q+0], Us[4*q+1], Us[4*q+2], Us[4*q+3]);
    }
    outU[(size_t)B*64 + b] = lj;
  }
}

extern "C" void kernel_launch(void* const* d_in, const int* in_sizes, int n_in,
                              void* d_out, int out_size, void* d_ws, size_t ws_size,
                              hipStream_t stream) {
  const void* U0  = d_in[0];
  const void* EPS = d_in[1];
  const void* W0  = d_in[2];
  const void* W1  = d_in[3];
  const void* W2  = d_in[4];
  float* ws = (float*)d_ws;
  int B = in_sizes[0] / 64;

  hipLaunchKernelGGL(prep_kernel, dim3(1), dim3(256), 0, stream, W0, W1, W2, ws);
  hipLaunchKernelGGL(flow_kernel, dim3((B + 63) / 64), dim3(64), 0, stream,
                     U0, EPS, ws, d_out, B);
}